// Round 9
// baseline (473.024 us; speedup 1.0000x reference)
//
#include <hip/hip_runtime.h>
#include <math.h>

// Problem constants (fixed by setup_inputs)
#define B_   64
#define N_   16384
#define C_   64
#define S_   16                    // N-splits for partial stats
#define ROWS_PER_BLK (N_ / S_)     // 1024 rows of C_ floats per stats block
#define EPS_ 1e-6f
#define ALPHA_MAX_ 0.5f

// clang native vector type — required by __builtin_nontemporal_{load,store}
// (HIP's float4 is a class and is rejected). Same 16B layout; supports
// .x/.y/.z/.w swizzles and elementwise arithmetic.
typedef float fvec4 __attribute__((ext_vector_type(4)));

// ---------------------------------------------------------------------------
// Kernel 1: per-(b, channel) partial sum / sumsq over an N-slice.
// Grid: B_*S_ blocks of 256 threads, perfectly coalesced nt float4 loads.
// Proven at ~6.2 TB/s (>=97% of the read ceiling). UNCHANGED — A/B discipline.
// ---------------------------------------------------------------------------
__global__ __launch_bounds__(256) void stats_partial_kernel(
    const float* __restrict__ x,
    float* __restrict__ sumP,   // [B_*S_][C_]
    float* __restrict__ sqP)    // [B_*S_][C_]
{
    const int bid = blockIdx.x;        // = b*S_ + s
    const int b   = bid >> 4;          // /S_ (S_==16)
    const int s   = bid & 15;

    const fvec4* xp = (const fvec4*)(x + ((size_t)b * N_ + (size_t)s * ROWS_PER_BLK) * C_);

    const int tid  = threadIdx.x;
    const int cg   = tid & 15;         // channel-group: covers channels cg*4..cg*4+3
    const int row0 = tid >> 4;         // 0..15

    fvec4 sum = (fvec4)(0.f);
    fvec4 sq  = (fvec4)(0.f);

    // Each row has C_/4 = 16 float4s; thread walks rows with stride 16.
    #pragma unroll 8
    for (int r = row0; r < ROWS_PER_BLK; r += 16) {
        fvec4 v = __builtin_nontemporal_load(xp + r * 16 + cg);
        sum += v;
        sq  += v * v;
    }

    __shared__ float lds[256][8];
    lds[tid][0] = sum.x; lds[tid][1] = sum.y; lds[tid][2] = sum.z; lds[tid][3] = sum.w;
    lds[tid][4] = sq.x;  lds[tid][5] = sq.y;  lds[tid][6] = sq.z;  lds[tid][7] = sq.w;
    __syncthreads();

    // Reduce across the 16 row-threads sharing each channel-group.
    // tid layout = row0*16 + cg, so strides of 16 preserve cg.
    for (int off = 128; off >= 16; off >>= 1) {
        if (tid < off) {
            #pragma unroll
            for (int k = 0; k < 8; ++k) lds[tid][k] += lds[tid + off][k];
        }
        __syncthreads();
    }

    if (tid < 16) {
        float* sp = sumP + (size_t)bid * C_ + tid * 4;
        float* qp = sqP  + (size_t)bid * C_ + tid * 4;
        sp[0] = lds[tid][0]; sp[1] = lds[tid][1]; sp[2] = lds[tid][2]; sp[3] = lds[tid][3];
        qp[0] = lds[tid][4]; qp[1] = lds[tid][5]; qp[2] = lds[tid][6]; qp[3] = lds[tid][7];
    }
}

// ---------------------------------------------------------------------------
// Kernel 2 (fused finalize + apply): each block owns a contiguous 128 KB
// chunk of one sample. Threads 0..63 recompute that sample's scale/bias from
// the partials (16 KiB, L2-resident; hidden under the first prefetch group).
//
// NEW this round: software-pipelined double-buffer main loop. Group k+1's
// 8 nt-loads are issued BEFORE group k's 8 nt-stores, so 8 loads stay in
// flight through every store phase — removes the read/write turnaround
// bubble at each group boundary (the remaining ~15% gap to the 6.29 TB/s
// copy µbench). Costs +32 VGPR (two 8-wide fvec4 buffers); occupancy drops
// ~8 -> ~6 blocks/CU, tolerable for a streaming kernel.
// nt on both streams (proven: stores +9.4 µs, loads +6.9 µs).
// ---------------------------------------------------------------------------
__global__ __launch_bounds__(256) void apply_fused_kernel(
    const float* __restrict__ x,
    const float* __restrict__ sumP,
    const float* __restrict__ sqP,
    const float* __restrict__ alpha_u,      // [B_]
    const float* __restrict__ select_noise, // [B_][B_]
    const int*   __restrict__ dom,          // [B_]
    const int*   __restrict__ cls,          // [B_]
    float* __restrict__ out)
{
    const int tid = threadIdx.x;
    const int b   = blockIdx.x >> 5;          // 32 blocks per sample

    const size_t base = (size_t)blockIdx.x * 8192 + tid;  // float4 index
    const fvec4* __restrict__ xin = (const fvec4*)x;
    fvec4* __restrict__ op = (fvec4*)out;

    fvec4 vA[8], vB[8];

    // ---- group 0 loads issued before scb (saturate HBM from t0) ----
    #pragma unroll
    for (int k = 0; k < 8; ++k)
        vA[k] = __builtin_nontemporal_load(xin + base + (size_t)k * 256);

    // ---- per-block scale/bias (threads 0..63, c = tid) ----
    __shared__ float scb[2][C_];
    if (tid < C_) {
        const int myCls = cls[b];
        const int myDom = dom[b];
        float best = -1.0f;   // noise is uniform[0,1), any valid score beats -1
        int   bi   = -1;
        for (int j = 0; j < B_; ++j) {
            if (cls[j] == myCls && dom[j] != myDom) {
                float sc = select_noise[b * B_ + j];
                if (sc > best) { best = sc; bi = j; }
            }
        }
        const int idx = (bi < 0) ? b : bi;

        double s1 = 0.0, q1 = 0.0, s2 = 0.0, q2 = 0.0;
        for (int s = 0; s < S_; ++s) {
            s1 += (double)sumP[((size_t)b   * S_ + s) * C_ + tid];
            q1 += (double)sqP [((size_t)b   * S_ + s) * C_ + tid];
            s2 += (double)sumP[((size_t)idx * S_ + s) * C_ + tid];
            q2 += (double)sqP [((size_t)idx * S_ + s) * C_ + tid];
        }
        const double n = (double)N_;
        const float mu   = (float)(s1 / n);
        const float sig  = sqrtf((float)((q1 - s1 * s1 / n) / (n - 1.0)) + EPS_);
        const float mu2  = (float)(s2 / n);
        const float sig2 = sqrtf((float)((q2 - s2 * s2 / n) / (n - 1.0)) + EPS_);

        const float a = alpha_u[b] * ALPHA_MAX_;
        const float mu_mix  = mu  * a + mu2  * (1.0f - a);
        const float sig_mix = sig * a + sig2 * (1.0f - a);

        const float scale = sig_mix / sig;
        scb[0][tid] = scale;
        scb[1][tid] = mu_mix - mu * scale;
    }
    __syncthreads();

    const int c0 = (tid & 15) * 4;
    fvec4 sc, bs;
    sc.x = scb[0][c0]; sc.y = scb[0][c0+1]; sc.z = scb[0][c0+2]; sc.w = scb[0][c0+3];
    bs.x = scb[1][c0]; bs.y = scb[1][c0+1]; bs.z = scb[1][c0+2]; bs.w = scb[1][c0+3];

    // ---- pipelined steady state: load group k+1, then store group k ----
    // group offsets (in float4-index units of 256): 0, 8, 16, 24
    #pragma unroll
    for (int k = 0; k < 8; ++k)
        vB[k] = __builtin_nontemporal_load(xin + base + (size_t)(8 + k) * 256);
    #pragma unroll
    for (int k = 0; k < 8; ++k)
        __builtin_nontemporal_store(vA[k] * sc + bs, op + base + (size_t)k * 256);

    #pragma unroll
    for (int k = 0; k < 8; ++k)
        vA[k] = __builtin_nontemporal_load(xin + base + (size_t)(16 + k) * 256);
    #pragma unroll
    for (int k = 0; k < 8; ++k)
        __builtin_nontemporal_store(vB[k] * sc + bs, op + base + (size_t)(8 + k) * 256);

    #pragma unroll
    for (int k = 0; k < 8; ++k)
        vB[k] = __builtin_nontemporal_load(xin + base + (size_t)(24 + k) * 256);
    #pragma unroll
    for (int k = 0; k < 8; ++k)
        __builtin_nontemporal_store(vA[k] * sc + bs, op + base + (size_t)(16 + k) * 256);

    #pragma unroll
    for (int k = 0; k < 8; ++k)
        __builtin_nontemporal_store(vB[k] * sc + bs, op + base + (size_t)(24 + k) * 256);
}

// ---------------------------------------------------------------------------
extern "C" void kernel_launch(void* const* d_in, const int* in_sizes, int n_in,
                              void* d_out, int out_size, void* d_ws, size_t ws_size,
                              hipStream_t stream) {
    const float* x            = (const float*)d_in[0];
    const float* alpha_u      = (const float*)d_in[1];
    const float* select_noise = (const float*)d_in[2];
    const int*   dom          = (const int*)d_in[3];
    const int*   cls          = (const int*)d_in[4];
    float* out = (float*)d_out;

    // Workspace layout (floats): sumP[B_*S_*C_], sqP[B_*S_*C_]
    float* sumP = (float*)d_ws;
    float* sqP  = sumP + (size_t)B_ * S_ * C_;          // +65536

    // 1) partial stats: 1024 blocks x 256 threads (nt loads)
    stats_partial_kernel<<<B_ * S_, 256, 0, stream>>>(x, sumP, sqP);

    // 2) fused finalize + apply: 2048 blocks x 256 threads (pipelined, nt both)
    apply_fused_kernel<<<2048, 256, 0, stream>>>(
        x, sumP, sqP, alpha_u, select_noise, dom, cls, out);
}